// Round 7
// baseline (772.028 us; speedup 1.0000x reference)
//
#include <hip/hip_runtime.h>
#include <hip/hip_bf16.h>

// GraphSAGE on MI355X — R7: degree-balanced gather scheduling (counting sort by
// degree -> perm; agg wave i processes perm[i], so co-resident waves have equal
// work), 4-deep prefetch gather, transpose-C MFMA epilogue, split-K 8 MLP1.
//
// Overlays after layer 3:
//   H4   = P0[0..32MB)          [2048x8192] bf16
//   T1   = P1[0..2MB)           [2048x256] fp32
//   pooled = P1+2MB             2048 fp32
//   PART = P1+4MB..P1+20MB      8 x [2048x256] fp32

#define NN 65536
#define EE 524288
#define ROWS 65537            // N + zero pad row
#define PCSR_CAP 720896       // E + 3*N upper bound

using frag16 = __attribute__((ext_vector_type(8))) short;   // 8 x bf16
using f32x4  = __attribute__((ext_vector_type(4))) float;

__device__ __forceinline__ float b2f(unsigned short u) {
    union { unsigned u32; float f; } x; x.u32 = (unsigned)u << 16; return x.f;
}

__device__ __forceinline__ unsigned short f2b(float f) {
    return (unsigned short)(__bfloat16_as_ushort(__float2bfloat16(f)));
}

__device__ __forceinline__ void gld_lds16(const void* g, void* l) {
    __builtin_amdgcn_global_load_lds(
        (const __attribute__((address_space(1))) void*)g,
        (__attribute__((address_space(3))) void*)l, 16, 0, 0);
}

// ---------------- graph prep ----------------

__global__ void gs_hist(const int* __restrict__ dst, int* __restrict__ deg) {
    int e = blockIdx.x * 256 + threadIdx.x;
    atomicAdd(&deg[dst[e]], 1);
}

// phase 1: per-block (256 nodes) sum of padded degrees -> bsum; degree histogram -> dhist
__global__ void gs_deg_reduce(const int* __restrict__ deg, int* __restrict__ bsum,
                              int* __restrict__ dhist) {
    __shared__ int lh[64];
    int t = threadIdx.x;
    if (t < 64) lh[t] = 0;
    __syncthreads();
    int d = deg[blockIdx.x * 256 + t];
    atomicAdd(&lh[min(d, 63)], 1);
    int p = (d + 3) & ~3;
#pragma unroll
    for (int off = 32; off > 0; off >>= 1) p += __shfl_down(p, off);
    __shared__ int w4[4];
    if ((t & 63) == 0) w4[t >> 6] = p;
    __syncthreads();
    if (t == 0) bsum[blockIdx.x] = w4[0] + w4[1] + w4[2] + w4[3];
    if (t < 64 && lh[t]) atomicAdd(&dhist[t], lh[t]);
}

// phase 2: scan 256 block sums -> bofs; descending exclusive scan of dhist -> dcur
__global__ void gs_scan_bsum(const int* __restrict__ bsum, int* __restrict__ bofs,
                             int* __restrict__ prow, const int* __restrict__ dhist,
                             int* __restrict__ dcur) {
    __shared__ int part[256];
    int t = threadIdx.x;
    int v = bsum[t];
    part[t] = v;
    __syncthreads();
    for (int off = 1; off < 256; off <<= 1) {
        int add = (t >= off) ? part[t - off] : 0;
        __syncthreads();
        part[t] += add;
        __syncthreads();
    }
    bofs[t] = part[t] - v;
    if (t == 255) prow[NN] = part[255];
    if (t == 0) {
        int run = 0;
        for (int b = 63; b >= 0; --b) { dcur[b] = run; run += dhist[b]; }
    }
}

// phase 3: per-block scan + apply; pad-fill segments; scatter perm; zero pad rows
__global__ void gs_scan_apply(const int* __restrict__ deg, const int* __restrict__ bofs,
                              int* __restrict__ prow, int* __restrict__ cursor,
                              float* __restrict__ inv_cnt, int* __restrict__ pcsr,
                              int* __restrict__ dcur, int* __restrict__ perm,
                              __hip_bfloat16* __restrict__ P0,
                              __hip_bfloat16* __restrict__ P1) {
    __shared__ int part[256];
    int t = threadIdx.x;
    int i = blockIdx.x * 256 + t;
    int d = deg[i];
    int p = (d + 3) & ~3;
    part[t] = p;
    __syncthreads();
    for (int off = 1; off < 256; off <<= 1) {
        int add = (t >= off) ? part[t - off] : 0;
        __syncthreads();
        part[t] += add;
        __syncthreads();
    }
    int beg = bofs[blockIdx.x] + part[t] - p;
    prow[i] = beg;
    cursor[i] = beg;
    inv_cnt[i] = 1.0f / (float)(d > 0 ? d : 1);
    for (int j = d; j < p; ++j) pcsr[beg + j] = NN;
    int pos = atomicAdd(&dcur[min(d, 63)], 1);
    perm[pos] = i;
    if (blockIdx.x == 0) {
        ((unsigned*)(P0 + (size_t)NN * 512))[t] = 0u;
        ((unsigned*)(P1 + (size_t)NN * 512))[t] = 0u;
    }
}

__global__ void gs_bucket(const int* __restrict__ src, const int* __restrict__ dst,
                          int* __restrict__ cursor, int* __restrict__ pcsr) {
    int e = blockIdx.x * 256 + threadIdx.x;
    int d = dst[e];
    int p = atomicAdd(&cursor[d], 1);
    pcsr[p] = src[e];
}

// ---------------- fused weight transpose+convert ----------------
struct TcvtArgs {
    const float* src[8];
    __hip_bfloat16* dst[8];
    int ldk[8];
    int kofs[8];
    int kblk[8];   // K/32
};

__global__ void gs_tcvt_all(TcvtArgs a) {
    int z = blockIdx.z;
    if ((int)blockIdx.x >= a.kblk[z]) return;
    const float* src = a.src[z];
    __hip_bfloat16* dst = a.dst[z];
    int ldk = a.ldk[z], kofs = a.kofs[z];
    __shared__ float tile[32][33];
    int kb = blockIdx.x * 32, nb = blockIdx.y * 32;
    int tx = threadIdx.x, ty = threadIdx.y;
#pragma unroll
    for (int i = 0; i < 32; i += 8)
        tile[ty + i][tx] = src[(size_t)(kb + ty + i) * 256 + nb + tx];
    __syncthreads();
#pragma unroll
    for (int i = 0; i < 32; i += 8) {
        int n = nb + ty + i, k = kb + tx;
        dst[(size_t)n * ldk + kofs + k] = __float2bfloat16(tile[tx][ty + i]);
    }
}

__global__ void gs_tcvt(const float* __restrict__ src, __hip_bfloat16* __restrict__ dst,
                        int ldk, int kofs) {
    __shared__ float tile[32][33];
    int kb = blockIdx.x * 32, nb = blockIdx.y * 32;
    int tx = threadIdx.x, ty = threadIdx.y;
#pragma unroll
    for (int i = 0; i < 32; i += 8)
        tile[ty + i][tx] = src[(size_t)(kb + ty + i) * 256 + nb + tx];
    __syncthreads();
#pragma unroll
    for (int i = 0; i < 32; i += 8) {
        int n = nb + ty + i, k = kb + tx;
        dst[(size_t)n * ldk + kofs + k] = __float2bfloat16(tile[tx][ty + i]);
    }
}

// ---------------- concat -> bf16 h0 at P0 cols 256..383 ----------------
__global__ void gs_concat_bf(const float* __restrict__ x, const float* __restrict__ g0,
                             const float* __restrict__ g1, const float* __restrict__ g2,
                             __hip_bfloat16* __restrict__ h) {
    int idx = blockIdx.x * 256 + threadIdx.x;   // N*128
    int n = idx >> 7, c = idx & 127;
    float v;
    if (c < 32)       v = x[n * 32 + c];
    else if (c < 64)  v = g0[n * 32 + (c - 32)];
    else if (c < 96)  v = g1[n * 32 + (c - 64)];
    else              v = g2[n * 32 + (c - 96)];
    h[(size_t)n * 512 + 256 + c] = __float2bfloat16(v);
}

// ---------------- mean aggregation: perm-scheduled, 4 edges/iter, index prefetch ----------
template <int DIM>
__global__ void gs_agg_bf(const __hip_bfloat16* __restrict__ hsrc,
                          __hip_bfloat16* __restrict__ adst,
                          const int* __restrict__ prow, const int* __restrict__ pcsr,
                          const float* __restrict__ inv_cnt,
                          const int* __restrict__ perm) {
    int wave = threadIdx.x >> 6;
    int lane = threadIdx.x & 63;
    int n = perm[blockIdx.x * 4 + wave];
    int e = prow[n], pe = prow[n + 1];
    float iv = inv_cnt[n];
    if constexpr (DIM == 256) {
        const __hip_bfloat16* base = hsrc + lane * 4;
        float a0 = 0.f, a1 = 0.f, a2 = 0.f, a3 = 0.f;
        int4 s4;
        if (e < pe) s4 = *(const int4*)(pcsr + e);
        while (e < pe) {
            int4 cur = s4;
            e += 4;
            if (e < pe) s4 = *(const int4*)(pcsr + e);
            ushort4 v0 = *(const ushort4*)(base + (size_t)cur.x * 512);
            ushort4 v1 = *(const ushort4*)(base + (size_t)cur.y * 512);
            ushort4 v2 = *(const ushort4*)(base + (size_t)cur.z * 512);
            ushort4 v3 = *(const ushort4*)(base + (size_t)cur.w * 512);
            a0 += b2f(v0.x); a1 += b2f(v0.y); a2 += b2f(v0.z); a3 += b2f(v0.w);
            a0 += b2f(v1.x); a1 += b2f(v1.y); a2 += b2f(v1.z); a3 += b2f(v1.w);
            a0 += b2f(v2.x); a1 += b2f(v2.y); a2 += b2f(v2.z); a3 += b2f(v2.w);
            a0 += b2f(v3.x); a1 += b2f(v3.y); a2 += b2f(v3.z); a3 += b2f(v3.w);
        }
        __hip_bfloat16 o[4] = {__float2bfloat16(a0 * iv), __float2bfloat16(a1 * iv),
                               __float2bfloat16(a2 * iv), __float2bfloat16(a3 * iv)};
        *(ushort4*)(adst + (size_t)n * 512 + lane * 4) = *(const ushort4*)o;
    } else {
        const __hip_bfloat16* base = hsrc + lane * 2;
        float a0 = 0.f, a1 = 0.f;
        int4 s4;
        if (e < pe) s4 = *(const int4*)(pcsr + e);
        while (e < pe) {
            int4 cur = s4;
            e += 4;
            if (e < pe) s4 = *(const int4*)(pcsr + e);
            ushort2 v0 = *(const ushort2*)(base + (size_t)cur.x * 512);
            ushort2 v1 = *(const ushort2*)(base + (size_t)cur.y * 512);
            ushort2 v2 = *(const ushort2*)(base + (size_t)cur.z * 512);
            ushort2 v3 = *(const ushort2*)(base + (size_t)cur.w * 512);
            a0 += b2f(v0.x); a1 += b2f(v0.y);
            a0 += b2f(v1.x); a1 += b2f(v1.y);
            a0 += b2f(v2.x); a1 += b2f(v2.y);
            a0 += b2f(v3.x); a1 += b2f(v3.y);
        }
        __hip_bfloat16 o[2] = {__float2bfloat16(a0 * iv), __float2bfloat16(a1 * iv)};
        *(ushort2*)(adst + (size_t)n * 512 + lane * 2) = *(const ushort2*)o;
    }
}

// ---------------- MFMA GEMM core: 128x128 tile, BK=64, 4 waves (2x2 of 64x64) ------------
// Operands swapped in the mfma call -> acc holds C^T fragments -> packed epilogue stores.
__device__ __forceinline__ void mfma_block(const __hip_bfloat16* A, int lda,
                                           const __hip_bfloat16* Bt, int ldb,
                                           int kbeg, int kend, size_t row0, size_t nbase,
                                           __hip_bfloat16* As, __hip_bfloat16* Bs,
                                           f32x4 acc[4][4]) {
    const int t = threadIdx.x;
    const int lane = t & 63;
    const int w = t >> 6;
    const int wr = (w >> 1) * 64;
    const int wc = (w & 1) * 64;
    const int srow = w * 32 + (lane >> 3);
    const int scol = (lane & 7) * 8;
    for (int kc = kbeg; kc < kend; kc += 64) {
#pragma unroll
        for (int l = 0; l < 4; ++l) {
            gld_lds16(A + (row0 + srow + 8 * l) * (size_t)lda + kc + scol,
                      As + (w * 32 + 8 * l) * 64);
            gld_lds16(Bt + (nbase + srow + 8 * l) * (size_t)ldb + kc + scol,
                      Bs + (w * 32 + 8 * l) * 64);
        }
        __syncthreads();
#pragma unroll
        for (int kk = 0; kk < 64; kk += 32) {
            frag16 af[4], bf[4];
#pragma unroll
            for (int i = 0; i < 4; ++i)
                af[i] = *(const frag16*)(As + (wr + i * 16 + (lane & 15)) * 64 + kk + (lane >> 4) * 8);
#pragma unroll
            for (int j = 0; j < 4; ++j)
                bf[j] = *(const frag16*)(Bs + (wc + j * 16 + (lane & 15)) * 64 + kk + (lane >> 4) * 8);
#pragma unroll
            for (int i = 0; i < 4; ++i)
#pragma unroll
                for (int j = 0; j < 4; ++j)
                    acc[i][j] = __builtin_amdgcn_mfma_f32_16x16x32_bf16(bf[j], af[i], acc[i][j], 0, 0, 0);
        }
        __syncthreads();
    }
}

__global__ __launch_bounds__(256, 2)
void gs_gemm_bias_relu(const __hip_bfloat16* __restrict__ A, int lda, int K,
                       const __hip_bfloat16* __restrict__ Bt, int ldb,
                       const float* __restrict__ bias,
                       __hip_bfloat16* __restrict__ C, int ldc, int cofs) {
    __shared__ __hip_bfloat16 As[128 * 64];
    __shared__ __hip_bfloat16 Bs[128 * 64];
    f32x4 acc[4][4] = {};
    const size_t row0 = (size_t)blockIdx.x * 128;
    const size_t nbase = (size_t)blockIdx.y * 128;
    mfma_block(A, lda, Bt, ldb, 0, K, row0, nbase, As, Bs, acc);
    const int lane = threadIdx.x & 63;
    const int w = threadIdx.x >> 6;
    const int wr = (w >> 1) * 64, wc = (w & 1) * 64;
#pragma unroll
    for (int j = 0; j < 4; ++j) {
        int nb = wc + j * 16 + (lane >> 4) * 4;
        const float4 bv = *(const float4*)&bias[(int)nbase + nb];
#pragma unroll
        for (int i = 0; i < 4; ++i) {
            int m = wr + i * 16 + (lane & 15);
            unsigned short o[4];
            o[0] = f2b(fmaxf(acc[i][j][0] + bv.x, 0.f));
            o[1] = f2b(fmaxf(acc[i][j][1] + bv.y, 0.f));
            o[2] = f2b(fmaxf(acc[i][j][2] + bv.z, 0.f));
            o[3] = f2b(fmaxf(acc[i][j][3] + bv.w, 0.f));
            *(ushort4*)(C + (row0 + m) * (size_t)ldc + cofs + nbase + nb) = *(const ushort4*)o;
        }
    }
}

// MLP1 split-K: grid (16, 2, 8); k-slice 1024; fp32 partials part[kz][2048][256]
__global__ __launch_bounds__(256, 2)
void gs_gemm_splitk(const __hip_bfloat16* __restrict__ A, int lda,
                    const __hip_bfloat16* __restrict__ Bt, int ldb,
                    float* __restrict__ part) {
    __shared__ __hip_bfloat16 As[128 * 64];
    __shared__ __hip_bfloat16 Bs[128 * 64];
    f32x4 acc[4][4] = {};
    const size_t row0 = (size_t)blockIdx.x * 128;
    const size_t nbase = (size_t)blockIdx.y * 128;
    const int kbeg = blockIdx.z * 1024;
    mfma_block(A, lda, Bt, ldb, kbeg, kbeg + 1024, row0, nbase, As, Bs, acc);
    const int lane = threadIdx.x & 63;
    const int w = threadIdx.x >> 6;
    const int wr = (w >> 1) * 64, wc = (w & 1) * 64;
    float* p = part + (size_t)blockIdx.z * 2048 * 256;
#pragma unroll
    for (int j = 0; j < 4; ++j) {
        int nb = wc + j * 16 + (lane >> 4) * 4;
#pragma unroll
        for (int i = 0; i < 4; ++i) {
            int m = wr + i * 16 + (lane & 15);
            *(f32x4*)(p + (row0 + m) * 256 + nbase + nb) = acc[i][j];
        }
    }
}

__global__ void gs_mlp1_reduce(const float* __restrict__ part, const float* __restrict__ b1,
                               float* __restrict__ t1) {
    int idx = blockIdx.x * 256 + threadIdx.x;   // 2048*256
    float s = 0.f;
#pragma unroll
    for (int ks = 0; ks < 8; ++ks) s += part[(size_t)ks * 524288 + idx];
    s += b1[idx & 255];
    t1[idx] = fmaxf(s, 0.f);
}

__global__ void gs_pool(const float* __restrict__ t1, const float* __restrict__ W2,
                        const float* __restrict__ b2, float* __restrict__ pooled) {
    int r = blockIdx.x;     // 2048
    int l = threadIdx.x;    // 64
    float acc = 0.f;
#pragma unroll
    for (int q = 0; q < 4; ++q) {
        int c = l + q * 64;
        acc = fmaf(t1[(size_t)r * 256 + c], W2[c], acc);
    }
    for (int off = 32; off > 0; off >>= 1) acc += __shfl_down(acc, off);
    if (l == 0) pooled[r] = acc + b2[0];
}

__global__ void gs_bn_mlp2(const float* __restrict__ pooled, const float* __restrict__ gamma,
                           const float* __restrict__ beta, const float* __restrict__ W1,
                           const float* __restrict__ b1, const float* __restrict__ W2,
                           const float* __restrict__ b2, float* __restrict__ out) {
    __shared__ float hb[8][256];
    __shared__ float h2[8][256];
    int t = threadIdx.x;    // 256
    {
        float v[8];
        float m = 0.f;
#pragma unroll
        for (int b = 0; b < 8; ++b) { v[b] = pooled[b * 256 + t]; m += v[b]; }
        m *= 0.125f;
        float var = 0.f;
#pragma unroll
        for (int b = 0; b < 8; ++b) { float d = v[b] - m; var += d * d; }
        var *= 0.125f;
        float is = 1.0f / sqrtf(var + 1e-5f);
        float g = gamma[t], bt = beta[t];
#pragma unroll
        for (int b = 0; b < 8; ++b) hb[b][t] = fmaxf((v[b] - m) * is * g + bt, 0.f);
    }
    __syncthreads();
    {
        float acc[8] = {};
        for (int i = 0; i < 256; ++i) {
            float w = W1[i * 256 + t];
#pragma unroll
            for (int b = 0; b < 8; ++b) acc[b] = fmaf(hb[b][i], w, acc[b]);
        }
        float bb = b1[t];
#pragma unroll
        for (int b = 0; b < 8; ++b) h2[b][t] = fmaxf(acc[b] + bb, 0.f);
    }
    __syncthreads();
    if (t < 64) {
        int b = t >> 3, o = t & 7;
        float acc = 0.f;
        for (int j = 0; j < 256; ++j) acc = fmaf(h2[b][j], W2[j * 8 + o], acc);
        out[b * 8 + o] = acc + b2[o];
    }
}

extern "C" void kernel_launch(void* const* d_in, const int* in_sizes, int n_in,
                              void* d_out, int out_size, void* d_ws, size_t ws_size,
                              hipStream_t stream) {
    const float* x  = (const float*)d_in[0];
    const float* g0 = (const float*)d_in[1];
    const float* g1 = (const float*)d_in[2];
    const float* g2 = (const float*)d_in[3];
    const int* edge_src = (const int*)d_in[4];
    const int* edge_dst = (const int*)d_in[5];
    const float* Wl[4] = {(const float*)d_in[6], (const float*)d_in[9],
                          (const float*)d_in[12], (const float*)d_in[15]};
    const float* Wr[4] = {(const float*)d_in[7], (const float*)d_in[10],
                          (const float*)d_in[13], (const float*)d_in[16]};
    const float* bs[4] = {(const float*)d_in[8], (const float*)d_in[11],
                          (const float*)d_in[14], (const float*)d_in[17]};
    const float* mlp1_W1 = (const float*)d_in[18];
    const float* mlp1_b1 = (const float*)d_in[19];
    const float* mlp1_W2 = (const float*)d_in[20];
    const float* mlp1_b2 = (const float*)d_in[21];
    const float* bn_gamma = (const float*)d_in[22];
    const float* bn_beta  = (const float*)d_in[23];
    const float* mlp2_W1 = (const float*)d_in[24];
    const float* mlp2_b1 = (const float*)d_in[25];
    const float* mlp2_W2 = (const float*)d_in[26];
    const float* mlp2_b2 = (const float*)d_in[27];
    float* out = (float*)d_out;

    char* ws = (char*)d_ws;
    __hip_bfloat16* P0 = (__hip_bfloat16*)ws;                  // [ROWS][512]
    __hip_bfloat16* P1 = P0 + (size_t)ROWS * 512;              // [ROWS][512]
    __hip_bfloat16* WC0 = P1 + (size_t)ROWS * 512;             // [256][256]
    __hip_bfloat16* WC1 = WC0 + 65536;                         // [256][512]
    __hip_bfloat16* WC2 = WC1 + 131072;
    __hip_bfloat16* WC3 = WC2 + 131072;
    __hip_bfloat16* W1T = WC3 + 131072;                        // [256][8192]
    float* inv_cnt = (float*)(W1T + 2097152);
    int* ideg = (int*)(inv_cnt + 65536);                       // [N]      -- memset 0
    int* dhist = ideg + 65536;                                 // [64]     -- memset 0
    int* dcur = dhist + 64;                                    // [64]
    int* prow = dcur + 64;                                     // 65537 (+pad)
    int* cursor = prow + 65544;
    int* bsum = cursor + 65536;                                // 256
    int* bofs = bsum + 256;                                    // 256
    int* perm = bofs + 256;                                    // [N]
    int* pcsr = perm + 65536;                                  // PCSR_CAP
    // overlays (all inside P0/P1, mutually disjoint):
    __hip_bfloat16* H4 = P0;                                   // [2048][8192] bf16 = 32 MB
    float* T1 = (float*)P1;                                    // [2048][256] fp32 = 2 MB
    float* pooled = T1 + 524288;                               // 8 KB at P1+2MB
    float* PART = (float*)((char*)P1 + (size_t)(4 << 20));     // 16 MB at P1+4MB

    // --- graph prep (zero ideg+dhist in one async memset; hierarchical scan; sort) ---
    hipMemsetAsync(ideg, 0, (65536 + 64) * sizeof(int), stream);
    gs_hist<<<EE / 256, 256, 0, stream>>>(edge_dst, ideg);
    gs_deg_reduce<<<256, 256, 0, stream>>>(ideg, bsum, dhist);
    gs_scan_bsum<<<1, 256, 0, stream>>>(bsum, bofs, prow, dhist, dcur);
    gs_scan_apply<<<256, 256, 0, stream>>>(ideg, bofs, prow, cursor, inv_cnt, pcsr,
                                           dcur, perm, P0, P1);
    gs_bucket<<<EE / 256, 256, 0, stream>>>(edge_src, edge_dst, cursor, pcsr);

    // --- weight conversion (one fused launch + W1T) ---
    {
        TcvtArgs a;
        const float* srcs[8] = {Wl[0], Wr[0], Wl[1], Wr[1], Wl[2], Wr[2], Wl[3], Wr[3]};
        __hip_bfloat16* dsts[8] = {WC0, WC0, WC1, WC1, WC2, WC2, WC3, WC3};
        int ldks[8] = {256, 256, 512, 512, 512, 512, 512, 512};
        int kofss[8] = {0, 128, 0, 256, 0, 256, 0, 256};
        int kblks[8] = {4, 4, 8, 8, 8, 8, 8, 8};
        for (int i = 0; i < 8; ++i) {
            a.src[i] = srcs[i]; a.dst[i] = dsts[i];
            a.ldk[i] = ldks[i]; a.kofs[i] = kofss[i]; a.kblk[i] = kblks[i];
        }
        gs_tcvt_all<<<dim3(8, 8, 8), dim3(32, 8), 0, stream>>>(a);
    }
    gs_tcvt<<<dim3(256, 8), dim3(32, 8), 0, stream>>>(mlp1_W1, W1T, 8192, 0);

    gs_concat_bf<<<NN * 128 / 256, 256, 0, stream>>>(x, g0, g1, g2, P0);

    // --- 4 SAGE layers ---
    gs_agg_bf<128><<<NN / 4, 256, 0, stream>>>(P0 + 256, P0 + 128, prow, pcsr, inv_cnt, perm);
    gs_gemm_bias_relu<<<dim3(NN / 128, 2), 256, 0, stream>>>(P0 + 128, 512, 256, WC0, 256,
                                                             bs[0], P1, 512, 256);
    gs_agg_bf<256><<<NN / 4, 256, 0, stream>>>(P1 + 256, P1, prow, pcsr, inv_cnt, perm);
    gs_gemm_bias_relu<<<dim3(NN / 128, 2), 256, 0, stream>>>(P1, 512, 512, WC1, 512,
                                                             bs[1], P0, 512, 256);
    gs_agg_bf<256><<<NN / 4, 256, 0, stream>>>(P0 + 256, P0, prow, pcsr, inv_cnt, perm);
    gs_gemm_bias_relu<<<dim3(NN / 128, 2), 256, 0, stream>>>(P0, 512, 512, WC2, 512,
                                                             bs[2], P1, 512, 256);
    gs_agg_bf<256><<<NN / 4, 256, 0, stream>>>(P1 + 256, P1, prow, pcsr, inv_cnt, perm);
    gs_gemm_bias_relu<<<dim3(NN / 128, 2), 256, 0, stream>>>(P1, 512, 512, WC3, 512,
                                                             bs[3], H4, 256, 0);

    // --- MLP1: [2048,8192] @ [8192,256] bf16 split-K=8 -> fp32 partials ---
    gs_gemm_splitk<<<dim3(16, 2, 8), 256, 0, stream>>>(H4, 8192, W1T, 8192, PART);
    gs_mlp1_reduce<<<2048, 256, 0, stream>>>(PART, mlp1_b1, T1);
    gs_pool<<<2048, 64, 0, stream>>>(T1, mlp1_W2, mlp1_b2, pooled);

    // --- BN + MLP2 -> out[8,8] ---
    gs_bn_mlp2<<<1, 256, 0, stream>>>(pooled, bn_gamma, bn_beta, mlp2_W1, mlp2_b1,
                                      mlp2_W2, mlp2_b2, out);
}

// Round 8
// 542.779 us; speedup vs baseline: 1.4224x; 1.4224x over previous
//
#include <hip/hip_runtime.h>
#include <hip/hip_bf16.h>

// GraphSAGE on MI355X — R8: R5 prep/agg (no degree sort) + R6 transpose-C epilogue
// + split-K 8 MLP1; agg index prefetch made unconditional (padded CSR + slack).
//
// Overlays after layer 3:
//   H4   = P0[0..32MB)          [2048x8192] bf16
//   T1   = P1[0..2MB)           [2048x256] fp32
//   pooled = P1+2MB             2048 fp32
//   PART = P1+4MB..P1+20MB      8 x [2048x256] fp32

#define NN 65536
#define EE 524288
#define ROWS 65537            // N + zero pad row
#define PCSR_CAP 720904       // E + 3*N upper bound + 8 slack (unconditional prefetch)

using frag16 = __attribute__((ext_vector_type(8))) short;   // 8 x bf16
using f32x4  = __attribute__((ext_vector_type(4))) float;

__device__ __forceinline__ float b2f(unsigned short u) {
    union { unsigned u32; float f; } x; x.u32 = (unsigned)u << 16; return x.f;
}

__device__ __forceinline__ unsigned short f2b(float f) {
    return (unsigned short)(__bfloat16_as_ushort(__float2bfloat16(f)));
}

__device__ __forceinline__ void gld_lds16(const void* g, void* l) {
    __builtin_amdgcn_global_load_lds(
        (const __attribute__((address_space(1))) void*)g,
        (__attribute__((address_space(3))) void*)l, 16, 0, 0);
}

// ---------------- graph prep ----------------

__global__ void gs_zero_deg(int* deg) {
    int i = blockIdx.x * 256 + threadIdx.x;
    if (i < NN) deg[i] = 0;
}

__global__ void gs_hist(const int* __restrict__ dst, int* __restrict__ deg) {
    int e = blockIdx.x * 256 + threadIdx.x;
    atomicAdd(&deg[dst[e]], 1);
}

// phase 1: per-block (256 nodes) sum of padded degrees -> bsum[256]
__global__ void gs_deg_reduce(const int* __restrict__ deg, int* __restrict__ bsum) {
    int t = threadIdx.x;
    int p = (deg[blockIdx.x * 256 + t] + 3) & ~3;
#pragma unroll
    for (int off = 32; off > 0; off >>= 1) p += __shfl_down(p, off);
    __shared__ int w4[4];
    if ((t & 63) == 0) w4[t >> 6] = p;
    __syncthreads();
    if (t == 0) bsum[blockIdx.x] = w4[0] + w4[1] + w4[2] + w4[3];
}

// phase 2: one block scans the 256 block sums -> bofs (exclusive), prow[NN]=total
__global__ void gs_scan_bsum(const int* __restrict__ bsum, int* __restrict__ bofs,
                             int* __restrict__ prow) {
    __shared__ int part[256];
    int t = threadIdx.x;
    int v = bsum[t];
    part[t] = v;
    __syncthreads();
    for (int off = 1; off < 256; off <<= 1) {
        int add = (t >= off) ? part[t - off] : 0;
        __syncthreads();
        part[t] += add;
        __syncthreads();
    }
    bofs[t] = part[t] - v;
    if (t == 255) prow[NN] = part[255];
}

// phase 3: per-block scan + apply; fill pad slots of each segment; zero pad rows
__global__ void gs_scan_apply(const int* __restrict__ deg, const int* __restrict__ bofs,
                              int* __restrict__ prow, int* __restrict__ cursor,
                              float* __restrict__ inv_cnt, int* __restrict__ pcsr,
                              __hip_bfloat16* __restrict__ P0,
                              __hip_bfloat16* __restrict__ P1) {
    __shared__ int part[256];
    int t = threadIdx.x;
    int i = blockIdx.x * 256 + t;
    int d = deg[i];
    int p = (d + 3) & ~3;
    part[t] = p;
    __syncthreads();
    for (int off = 1; off < 256; off <<= 1) {
        int add = (t >= off) ? part[t - off] : 0;
        __syncthreads();
        part[t] += add;
        __syncthreads();
    }
    int beg = bofs[blockIdx.x] + part[t] - p;
    prow[i] = beg;
    cursor[i] = beg;
    inv_cnt[i] = 1.0f / (float)(d > 0 ? d : 1);
    for (int j = d; j < p; ++j) pcsr[beg + j] = NN;
    if (blockIdx.x == 0) {
        ((unsigned*)(P0 + (size_t)NN * 512))[t] = 0u;
        ((unsigned*)(P1 + (size_t)NN * 512))[t] = 0u;
        if (t < 8) pcsr[PCSR_CAP - 8 + t] = NN;   // slack for unconditional prefetch
    }
}

__global__ void gs_bucket(const int* __restrict__ src, const int* __restrict__ dst,
                          int* __restrict__ cursor, int* __restrict__ pcsr) {
    int e = blockIdx.x * 256 + threadIdx.x;
    int d = dst[e];
    int p = atomicAdd(&cursor[d], 1);
    pcsr[p] = src[e];
}

// ---------------- fused weight transpose+convert ----------------
struct TcvtArgs {
    const float* src[8];
    __hip_bfloat16* dst[8];
    int ldk[8];
    int kofs[8];
    int kblk[8];   // K/32
};

__global__ void gs_tcvt_all(TcvtArgs a) {
    int z = blockIdx.z;
    if ((int)blockIdx.x >= a.kblk[z]) return;
    const float* src = a.src[z];
    __hip_bfloat16* dst = a.dst[z];
    int ldk = a.ldk[z], kofs = a.kofs[z];
    __shared__ float tile[32][33];
    int kb = blockIdx.x * 32, nb = blockIdx.y * 32;
    int tx = threadIdx.x, ty = threadIdx.y;
#pragma unroll
    for (int i = 0; i < 32; i += 8)
        tile[ty + i][tx] = src[(size_t)(kb + ty + i) * 256 + nb + tx];
    __syncthreads();
#pragma unroll
    for (int i = 0; i < 32; i += 8) {
        int n = nb + ty + i, k = kb + tx;
        dst[(size_t)n * ldk + kofs + k] = __float2bfloat16(tile[tx][ty + i]);
    }
}

__global__ void gs_tcvt(const float* __restrict__ src, __hip_bfloat16* __restrict__ dst,
                        int ldk, int kofs) {
    __shared__ float tile[32][33];
    int kb = blockIdx.x * 32, nb = blockIdx.y * 32;
    int tx = threadIdx.x, ty = threadIdx.y;
#pragma unroll
    for (int i = 0; i < 32; i += 8)
        tile[ty + i][tx] = src[(size_t)(kb + ty + i) * 256 + nb + tx];
    __syncthreads();
#pragma unroll
    for (int i = 0; i < 32; i += 8) {
        int n = nb + ty + i, k = kb + tx;
        dst[(size_t)n * ldk + kofs + k] = __float2bfloat16(tile[tx][ty + i]);
    }
}

// ---------------- concat -> bf16 h0 at P0 cols 256..383 ----------------
__global__ void gs_concat_bf(const float* __restrict__ x, const float* __restrict__ g0,
                             const float* __restrict__ g1, const float* __restrict__ g2,
                             __hip_bfloat16* __restrict__ h) {
    int idx = blockIdx.x * 256 + threadIdx.x;   // N*128
    int n = idx >> 7, c = idx & 127;
    float v;
    if (c < 32)       v = x[n * 32 + c];
    else if (c < 64)  v = g0[n * 32 + (c - 32)];
    else if (c < 96)  v = g1[n * 32 + (c - 64)];
    else              v = g2[n * 32 + (c - 96)];
    h[(size_t)n * 512 + 256 + c] = __float2bfloat16(v);
}

// ---------------- mean aggregation: 4 edges/iter, unconditional index prefetch ----------
template <int DIM>
__global__ void gs_agg_bf(const __hip_bfloat16* __restrict__ hsrc,
                          __hip_bfloat16* __restrict__ adst,
                          const int* __restrict__ prow, const int* __restrict__ pcsr,
                          const float* __restrict__ inv_cnt) {
    int wave = threadIdx.x >> 6;
    int lane = threadIdx.x & 63;
    int n = blockIdx.x * 4 + wave;
    int e = prow[n], pe = prow[n + 1];
    float iv = inv_cnt[n];
    if constexpr (DIM == 256) {
        const __hip_bfloat16* base = hsrc + lane * 4;
        float a0 = 0.f, a1 = 0.f, a2 = 0.f, a3 = 0.f;
        int4 s4 = *(const int4*)(pcsr + e);      // benign over-read if segment empty
        while (e < pe) {
            int4 cur = s4;
            e += 4;
            s4 = *(const int4*)(pcsr + e);       // unconditional; slack-backed at tail
            ushort4 v0 = *(const ushort4*)(base + (size_t)cur.x * 512);
            ushort4 v1 = *(const ushort4*)(base + (size_t)cur.y * 512);
            ushort4 v2 = *(const ushort4*)(base + (size_t)cur.z * 512);
            ushort4 v3 = *(const ushort4*)(base + (size_t)cur.w * 512);
            a0 += b2f(v0.x); a1 += b2f(v0.y); a2 += b2f(v0.z); a3 += b2f(v0.w);
            a0 += b2f(v1.x); a1 += b2f(v1.y); a2 += b2f(v1.z); a3 += b2f(v1.w);
            a0 += b2f(v2.x); a1 += b2f(v2.y); a2 += b2f(v2.z); a3 += b2f(v2.w);
            a0 += b2f(v3.x); a1 += b2f(v3.y); a2 += b2f(v3.z); a3 += b2f(v3.w);
        }
        __hip_bfloat16 o[4] = {__float2bfloat16(a0 * iv), __float2bfloat16(a1 * iv),
                               __float2bfloat16(a2 * iv), __float2bfloat16(a3 * iv)};
        *(ushort4*)(adst + (size_t)n * 512 + lane * 4) = *(const ushort4*)o;
    } else {
        const __hip_bfloat16* base = hsrc + lane * 2;
        float a0 = 0.f, a1 = 0.f;
        int4 s4 = *(const int4*)(pcsr + e);
        while (e < pe) {
            int4 cur = s4;
            e += 4;
            s4 = *(const int4*)(pcsr + e);
            ushort2 v0 = *(const ushort2*)(base + (size_t)cur.x * 512);
            ushort2 v1 = *(const ushort2*)(base + (size_t)cur.y * 512);
            ushort2 v2 = *(const ushort2*)(base + (size_t)cur.z * 512);
            ushort2 v3 = *(const ushort2*)(base + (size_t)cur.w * 512);
            a0 += b2f(v0.x); a1 += b2f(v0.y);
            a0 += b2f(v1.x); a1 += b2f(v1.y);
            a0 += b2f(v2.x); a1 += b2f(v2.y);
            a0 += b2f(v3.x); a1 += b2f(v3.y);
        }
        __hip_bfloat16 o[2] = {__float2bfloat16(a0 * iv), __float2bfloat16(a1 * iv)};
        *(ushort2*)(adst + (size_t)n * 512 + lane * 2) = *(const ushort2*)o;
    }
}

// ---------------- MFMA GEMM core: 128x128 tile, BK=64, 4 waves (2x2 of 64x64) ------------
// Operands swapped in the mfma call -> acc holds C^T fragments -> packed epilogue stores.
__device__ __forceinline__ void mfma_block(const __hip_bfloat16* A, int lda,
                                           const __hip_bfloat16* Bt, int ldb,
                                           int kbeg, int kend, size_t row0, size_t nbase,
                                           __hip_bfloat16* As, __hip_bfloat16* Bs,
                                           f32x4 acc[4][4]) {
    const int t = threadIdx.x;
    const int lane = t & 63;
    const int w = t >> 6;
    const int wr = (w >> 1) * 64;
    const int wc = (w & 1) * 64;
    const int srow = w * 32 + (lane >> 3);
    const int scol = (lane & 7) * 8;
    for (int kc = kbeg; kc < kend; kc += 64) {
#pragma unroll
        for (int l = 0; l < 4; ++l) {
            gld_lds16(A + (row0 + srow + 8 * l) * (size_t)lda + kc + scol,
                      As + (w * 32 + 8 * l) * 64);
            gld_lds16(Bt + (nbase + srow + 8 * l) * (size_t)ldb + kc + scol,
                      Bs + (w * 32 + 8 * l) * 64);
        }
        __syncthreads();
#pragma unroll
        for (int kk = 0; kk < 64; kk += 32) {
            frag16 af[4], bf[4];
#pragma unroll
            for (int i = 0; i < 4; ++i)
                af[i] = *(const frag16*)(As + (wr + i * 16 + (lane & 15)) * 64 + kk + (lane >> 4) * 8);
#pragma unroll
            for (int j = 0; j < 4; ++j)
                bf[j] = *(const frag16*)(Bs + (wc + j * 16 + (lane & 15)) * 64 + kk + (lane >> 4) * 8);
#pragma unroll
            for (int i = 0; i < 4; ++i)
#pragma unroll
                for (int j = 0; j < 4; ++j)
                    acc[i][j] = __builtin_amdgcn_mfma_f32_16x16x32_bf16(bf[j], af[i], acc[i][j], 0, 0, 0);
        }
        __syncthreads();
    }
}

__global__ __launch_bounds__(256, 2)
void gs_gemm_bias_relu(const __hip_bfloat16* __restrict__ A, int lda, int K,
                       const __hip_bfloat16* __restrict__ Bt, int ldb,
                       const float* __restrict__ bias,
                       __hip_bfloat16* __restrict__ C, int ldc, int cofs) {
    __shared__ __hip_bfloat16 As[128 * 64];
    __shared__ __hip_bfloat16 Bs[128 * 64];
    f32x4 acc[4][4] = {};
    const size_t row0 = (size_t)blockIdx.x * 128;
    const size_t nbase = (size_t)blockIdx.y * 128;
    mfma_block(A, lda, Bt, ldb, 0, K, row0, nbase, As, Bs, acc);
    const int lane = threadIdx.x & 63;
    const int w = threadIdx.x >> 6;
    const int wr = (w >> 1) * 64, wc = (w & 1) * 64;
#pragma unroll
    for (int j = 0; j < 4; ++j) {
        int nb = wc + j * 16 + (lane >> 4) * 4;
        const float4 bv = *(const float4*)&bias[(int)nbase + nb];
#pragma unroll
        for (int i = 0; i < 4; ++i) {
            int m = wr + i * 16 + (lane & 15);
            unsigned short o[4];
            o[0] = f2b(fmaxf(acc[i][j][0] + bv.x, 0.f));
            o[1] = f2b(fmaxf(acc[i][j][1] + bv.y, 0.f));
            o[2] = f2b(fmaxf(acc[i][j][2] + bv.z, 0.f));
            o[3] = f2b(fmaxf(acc[i][j][3] + bv.w, 0.f));
            *(ushort4*)(C + (row0 + m) * (size_t)ldc + cofs + nbase + nb) = *(const ushort4*)o;
        }
    }
}

// MLP1 split-K: grid (16, 2, 8); k-slice 1024; fp32 partials part[kz][2048][256]
__global__ __launch_bounds__(256, 2)
void gs_gemm_splitk(const __hip_bfloat16* __restrict__ A, int lda,
                    const __hip_bfloat16* __restrict__ Bt, int ldb,
                    float* __restrict__ part) {
    __shared__ __hip_bfloat16 As[128 * 64];
    __shared__ __hip_bfloat16 Bs[128 * 64];
    f32x4 acc[4][4] = {};
    const size_t row0 = (size_t)blockIdx.x * 128;
    const size_t nbase = (size_t)blockIdx.y * 128;
    const int kbeg = blockIdx.z * 1024;
    mfma_block(A, lda, Bt, ldb, kbeg, kbeg + 1024, row0, nbase, As, Bs, acc);
    const int lane = threadIdx.x & 63;
    const int w = threadIdx.x >> 6;
    const int wr = (w >> 1) * 64, wc = (w & 1) * 64;
    float* p = part + (size_t)blockIdx.z * 2048 * 256;
#pragma unroll
    for (int j = 0; j < 4; ++j) {
        int nb = wc + j * 16 + (lane >> 4) * 4;
#pragma unroll
        for (int i = 0; i < 4; ++i) {
            int m = wr + i * 16 + (lane & 15);
            *(f32x4*)(p + (row0 + m) * 256 + nbase + nb) = acc[i][j];
        }
    }
}

__global__ void gs_mlp1_reduce(const float* __restrict__ part, const float* __restrict__ b1,
                               float* __restrict__ t1) {
    int idx = blockIdx.x * 256 + threadIdx.x;   // 2048*256
    float s = 0.f;
#pragma unroll
    for (int ks = 0; ks < 8; ++ks) s += part[(size_t)ks * 524288 + idx];
    s += b1[idx & 255];
    t1[idx] = fmaxf(s, 0.f);
}

__global__ void gs_pool(const float* __restrict__ t1, const float* __restrict__ W2,
                        const float* __restrict__ b2, float* __restrict__ pooled) {
    int r = blockIdx.x;     // 2048
    int l = threadIdx.x;    // 64
    float acc = 0.f;
#pragma unroll
    for (int q = 0; q < 4; ++q) {
        int c = l + q * 64;
        acc = fmaf(t1[(size_t)r * 256 + c], W2[c], acc);
    }
    for (int off = 32; off > 0; off >>= 1) acc += __shfl_down(acc, off);
    if (l == 0) pooled[r] = acc + b2[0];
}

__global__ void gs_bn_mlp2(const float* __restrict__ pooled, const float* __restrict__ gamma,
                           const float* __restrict__ beta, const float* __restrict__ W1,
                           const float* __restrict__ b1, const float* __restrict__ W2,
                           const float* __restrict__ b2, float* __restrict__ out) {
    __shared__ float hb[8][256];
    __shared__ float h2[8][256];
    int t = threadIdx.x;    // 256
    {
        float v[8];
        float m = 0.f;
#pragma unroll
        for (int b = 0; b < 8; ++b) { v[b] = pooled[b * 256 + t]; m += v[b]; }
        m *= 0.125f;
        float var = 0.f;
#pragma unroll
        for (int b = 0; b < 8; ++b) { float d = v[b] - m; var += d * d; }
        var *= 0.125f;
        float is = 1.0f / sqrtf(var + 1e-5f);
        float g = gamma[t], bt = beta[t];
#pragma unroll
        for (int b = 0; b < 8; ++b) hb[b][t] = fmaxf((v[b] - m) * is * g + bt, 0.f);
    }
    __syncthreads();
    {
        float acc[8] = {};
        for (int i = 0; i < 256; ++i) {
            float w = W1[i * 256 + t];
#pragma unroll
            for (int b = 0; b < 8; ++b) acc[b] = fmaf(hb[b][i], w, acc[b]);
        }
        float bb = b1[t];
#pragma unroll
        for (int b = 0; b < 8; ++b) h2[b][t] = fmaxf(acc[b] + bb, 0.f);
    }
    __syncthreads();
    if (t < 64) {
        int b = t >> 3, o = t & 7;
        float acc = 0.f;
        for (int j = 0; j < 256; ++j) acc = fmaf(h2[b][j], W2[j * 8 + o], acc);
        out[b * 8 + o] = acc + b2[o];
    }
}

extern "C" void kernel_launch(void* const* d_in, const int* in_sizes, int n_in,
                              void* d_out, int out_size, void* d_ws, size_t ws_size,
                              hipStream_t stream) {
    const float* x  = (const float*)d_in[0];
    const float* g0 = (const float*)d_in[1];
    const float* g1 = (const float*)d_in[2];
    const float* g2 = (const float*)d_in[3];
    const int* edge_src = (const int*)d_in[4];
    const int* edge_dst = (const int*)d_in[5];
    const float* Wl[4] = {(const float*)d_in[6], (const float*)d_in[9],
                          (const float*)d_in[12], (const float*)d_in[15]};
    const float* Wr[4] = {(const float*)d_in[7], (const float*)d_in[10],
                          (const float*)d_in[13], (const float*)d_in[16]};
    const float* bs[4] = {(const float*)d_in[8], (const float*)d_in[11],
                          (const float*)d_in[14], (const float*)d_in[17]};
    const float* mlp1_W1 = (const float*)d_in[18];
    const float* mlp1_b1 = (const float*)d_in[19];
    const float* mlp1_W2 = (const float*)d_in[20];
    const float* mlp1_b2 = (const float*)d_in[21];
    const float* bn_gamma = (const float*)d_in[22];
    const float* bn_beta  = (const float*)d_in[23];
    const float* mlp2_W1 = (const float*)d_in[24];
    const float* mlp2_b1 = (const float*)d_in[25];
    const float* mlp2_W2 = (const float*)d_in[26];
    const float* mlp2_b2 = (const float*)d_in[27];
    float* out = (float*)d_out;

    char* ws = (char*)d_ws;
    __hip_bfloat16* P0 = (__hip_bfloat16*)ws;                  // [ROWS][512]
    __hip_bfloat16* P1 = P0 + (size_t)ROWS * 512;              // [ROWS][512]
    __hip_bfloat16* WC0 = P1 + (size_t)ROWS * 512;             // [256][256]
    __hip_bfloat16* WC1 = WC0 + 65536;                         // [256][512]
    __hip_bfloat16* WC2 = WC1 + 131072;
    __hip_bfloat16* WC3 = WC2 + 131072;
    __hip_bfloat16* W1T = WC3 + 131072;                        // [256][8192]
    float* inv_cnt = (float*)(W1T + 2097152);
    int* ideg = (int*)(inv_cnt + 65536);
    int* prow = ideg + 65536;                                  // 65537 (+pad)
    int* cursor = prow + 65544;
    int* bsum = cursor + 65536;                                // 256
    int* bofs = bsum + 256;                                    // 256
    int* pcsr = bofs + 256;                                    // PCSR_CAP (incl. slack)
    // overlays (all inside P0/P1, mutually disjoint):
    __hip_bfloat16* H4 = P0;                                   // [2048][8192] bf16 = 32 MB
    float* T1 = (float*)P1;                                    // [2048][256] fp32 = 2 MB
    float* pooled = T1 + 524288;                               // 8 KB at P1+2MB
    float* PART = (float*)((char*)P1 + (size_t)(4 << 20));     // 16 MB at P1+4MB

    // --- graph prep (hierarchical scan; apply pad-fills pcsr + zeroes pad rows) ---
    gs_zero_deg<<<256, 256, 0, stream>>>(ideg);
    gs_hist<<<EE / 256, 256, 0, stream>>>(edge_dst, ideg);
    gs_deg_reduce<<<256, 256, 0, stream>>>(ideg, bsum);
    gs_scan_bsum<<<1, 256, 0, stream>>>(bsum, bofs, prow);
    gs_scan_apply<<<256, 256, 0, stream>>>(ideg, bofs, prow, cursor, inv_cnt, pcsr, P0, P1);
    gs_bucket<<<EE / 256, 256, 0, stream>>>(edge_src, edge_dst, cursor, pcsr);

    // --- weight conversion (one fused launch + W1T) ---
    {
        TcvtArgs a;
        const float* srcs[8] = {Wl[0], Wr[0], Wl[1], Wr[1], Wl[2], Wr[2], Wl[3], Wr[3]};
        __hip_bfloat16* dsts[8] = {WC0, WC0, WC1, WC1, WC2, WC2, WC3, WC3};
        int ldks[8] = {256, 256, 512, 512, 512, 512, 512, 512};
        int kofss[8] = {0, 128, 0, 256, 0, 256, 0, 256};
        int kblks[8] = {4, 4, 8, 8, 8, 8, 8, 8};
        for (int i = 0; i < 8; ++i) {
            a.src[i] = srcs[i]; a.dst[i] = dsts[i];
            a.ldk[i] = ldks[i]; a.kofs[i] = kofss[i]; a.kblk[i] = kblks[i];
        }
        gs_tcvt_all<<<dim3(8, 8, 8), dim3(32, 8), 0, stream>>>(a);
    }
    gs_tcvt<<<dim3(256, 8), dim3(32, 8), 0, stream>>>(mlp1_W1, W1T, 8192, 0);

    gs_concat_bf<<<NN * 128 / 256, 256, 0, stream>>>(x, g0, g1, g2, P0);

    // --- 4 SAGE layers ---
    gs_agg_bf<128><<<NN / 4, 256, 0, stream>>>(P0 + 256, P0 + 128, prow, pcsr, inv_cnt);
    gs_gemm_bias_relu<<<dim3(NN / 128, 2), 256, 0, stream>>>(P0 + 128, 512, 256, WC0, 256,
                                                             bs[0], P1, 512, 256);
    gs_agg_bf<256><<<NN / 4, 256, 0, stream>>>(P1 + 256, P1, prow, pcsr, inv_cnt);
    gs_gemm_bias_relu<<<dim3(NN / 128, 2), 256, 0, stream>>>(P1, 512, 512, WC1, 512,
                                                             bs[1], P0, 512, 256);
    gs_agg_bf<256><<<NN / 4, 256, 0, stream>>>(P0 + 256, P0, prow, pcsr, inv_cnt);
    gs_gemm_bias_relu<<<dim3(NN / 128, 2), 256, 0, stream>>>(P0, 512, 512, WC2, 512,
                                                             bs[2], P1, 512, 256);
    gs_agg_bf<256><<<NN / 4, 256, 0, stream>>>(P1 + 256, P1, prow, pcsr, inv_cnt);
    gs_gemm_bias_relu<<<dim3(NN / 128, 2), 256, 0, stream>>>(P1, 512, 512, WC3, 512,
                                                             bs[3], H4, 256, 0);

    // --- MLP1: [2048,8192] @ [8192,256] bf16 split-K=8 -> fp32 partials ---
    gs_gemm_splitk<<<dim3(16, 2, 8), 256, 0, stream>>>(H4, 8192, W1T, 8192, PART);
    gs_mlp1_reduce<<<2048, 256, 0, stream>>>(PART, mlp1_b1, T1);
    gs_pool<<<2048, 64, 0, stream>>>(T1, mlp1_W2, mlp1_b2, pooled);

    // --- BN + MLP2 -> out[8,8] ---
    gs_bn_mlp2<<<1, 256, 0, stream>>>(pooled, bn_gamma, bn_beta, mlp2_W1, mlp2_b1,
                                      mlp2_W2, mlp2_b2, out);
}

// Round 9
// 531.101 us; speedup vs baseline: 1.4536x; 1.0220x over previous
//
#include <hip/hip_runtime.h>
#include <hip/hip_bf16.h>

// GraphSAGE on MI355X — R9: N-tile-256 layer GEMM (A read once), fused MLP1
// reduce+pool, branchless 8-deep gather (pad-to-8 CSR segments -> zero row).
//
// Overlays after layer 3:
//   H4   = P0[0..32MB)          [2048x8192] bf16
//   pooled = P1+2MB             2048 fp32
//   PART = P1+4MB..P1+36MB      16 x [2048x256] fp32

#define NN 65536
#define EE 524288
#define ROWS 65537             // N + zero pad row
#define PCSR_CAP 983056        // E + 7*N + 16 slack (pad-to-8 + unconditional prefetch)

using frag16 = __attribute__((ext_vector_type(8))) short;   // 8 x bf16
using f32x4  = __attribute__((ext_vector_type(4))) float;

__device__ __forceinline__ float b2f(unsigned short u) {
    union { unsigned u32; float f; } x; x.u32 = (unsigned)u << 16; return x.f;
}

__device__ __forceinline__ unsigned short f2b(float f) {
    return (unsigned short)(__bfloat16_as_ushort(__float2bfloat16(f)));
}

__device__ __forceinline__ void gld_lds16(const void* g, void* l) {
    __builtin_amdgcn_global_load_lds(
        (const __attribute__((address_space(1))) void*)g,
        (__attribute__((address_space(3))) void*)l, 16, 0, 0);
}

// ---------------- graph prep ----------------

__global__ void gs_zero_deg(int* deg) {
    int i = blockIdx.x * 256 + threadIdx.x;
    if (i < NN) deg[i] = 0;
}

__global__ void gs_hist(const int* __restrict__ dst, int* __restrict__ deg) {
    int e = blockIdx.x * 256 + threadIdx.x;
    atomicAdd(&deg[dst[e]], 1);
}

// phase 1: per-block (256 nodes) sum of pad-8 degrees -> bsum[256]
__global__ void gs_deg_reduce(const int* __restrict__ deg, int* __restrict__ bsum) {
    int t = threadIdx.x;
    int p = (deg[blockIdx.x * 256 + t] + 7) & ~7;
#pragma unroll
    for (int off = 32; off > 0; off >>= 1) p += __shfl_down(p, off);
    __shared__ int w4[4];
    if ((t & 63) == 0) w4[t >> 6] = p;
    __syncthreads();
    if (t == 0) bsum[blockIdx.x] = w4[0] + w4[1] + w4[2] + w4[3];
}

// phase 2: one block scans the 256 block sums -> bofs (exclusive), prow[NN]=total
__global__ void gs_scan_bsum(const int* __restrict__ bsum, int* __restrict__ bofs,
                             int* __restrict__ prow) {
    __shared__ int part[256];
    int t = threadIdx.x;
    int v = bsum[t];
    part[t] = v;
    __syncthreads();
    for (int off = 1; off < 256; off <<= 1) {
        int add = (t >= off) ? part[t - off] : 0;
        __syncthreads();
        part[t] += add;
        __syncthreads();
    }
    bofs[t] = part[t] - v;
    if (t == 255) prow[NN] = part[255];
}

// phase 3: per-block scan + apply; fill pad slots of each segment; zero pad rows
__global__ void gs_scan_apply(const int* __restrict__ deg, const int* __restrict__ bofs,
                              int* __restrict__ prow, int* __restrict__ cursor,
                              float* __restrict__ inv_cnt, int* __restrict__ pcsr,
                              __hip_bfloat16* __restrict__ P0,
                              __hip_bfloat16* __restrict__ P1) {
    __shared__ int part[256];
    int t = threadIdx.x;
    int i = blockIdx.x * 256 + t;
    int d = deg[i];
    int p = (d + 7) & ~7;
    part[t] = p;
    __syncthreads();
    for (int off = 1; off < 256; off <<= 1) {
        int add = (t >= off) ? part[t - off] : 0;
        __syncthreads();
        part[t] += add;
        __syncthreads();
    }
    int beg = bofs[blockIdx.x] + part[t] - p;
    prow[i] = beg;
    cursor[i] = beg;
    inv_cnt[i] = 1.0f / (float)(d > 0 ? d : 1);
    for (int j = d; j < p; ++j) pcsr[beg + j] = NN;
    if (blockIdx.x == 0) {
        ((unsigned*)(P0 + (size_t)NN * 512))[t] = 0u;
        ((unsigned*)(P1 + (size_t)NN * 512))[t] = 0u;
        if (t < 16) pcsr[PCSR_CAP - 16 + t] = NN;   // slack for unconditional prefetch
    }
}

__global__ void gs_bucket(const int* __restrict__ src, const int* __restrict__ dst,
                          int* __restrict__ cursor, int* __restrict__ pcsr) {
    int e = blockIdx.x * 256 + threadIdx.x;
    int d = dst[e];
    int p = atomicAdd(&cursor[d], 1);
    pcsr[p] = src[e];
}

// ---------------- fused weight transpose+convert ----------------
struct TcvtArgs {
    const float* src[8];
    __hip_bfloat16* dst[8];
    int ldk[8];
    int kofs[8];
    int kblk[8];   // K/32
};

__global__ void gs_tcvt_all(TcvtArgs a) {
    int z = blockIdx.z;
    if ((int)blockIdx.x >= a.kblk[z]) return;
    const float* src = a.src[z];
    __hip_bfloat16* dst = a.dst[z];
    int ldk = a.ldk[z], kofs = a.kofs[z];
    __shared__ float tile[32][33];
    int kb = blockIdx.x * 32, nb = blockIdx.y * 32;
    int tx = threadIdx.x, ty = threadIdx.y;
#pragma unroll
    for (int i = 0; i < 32; i += 8)
        tile[ty + i][tx] = src[(size_t)(kb + ty + i) * 256 + nb + tx];
    __syncthreads();
#pragma unroll
    for (int i = 0; i < 32; i += 8) {
        int n = nb + ty + i, k = kb + tx;
        dst[(size_t)n * ldk + kofs + k] = __float2bfloat16(tile[tx][ty + i]);
    }
}

__global__ void gs_tcvt(const float* __restrict__ src, __hip_bfloat16* __restrict__ dst,
                        int ldk, int kofs) {
    __shared__ float tile[32][33];
    int kb = blockIdx.x * 32, nb = blockIdx.y * 32;
    int tx = threadIdx.x, ty = threadIdx.y;
#pragma unroll
    for (int i = 0; i < 32; i += 8)
        tile[ty + i][tx] = src[(size_t)(kb + ty + i) * 256 + nb + tx];
    __syncthreads();
#pragma unroll
    for (int i = 0; i < 32; i += 8) {
        int n = nb + ty + i, k = kb + tx;
        dst[(size_t)n * ldk + kofs + k] = __float2bfloat16(tile[tx][ty + i]);
    }
}

// ---------------- concat -> bf16 h0 at P0 cols 256..383 ----------------
__global__ void gs_concat_bf(const float* __restrict__ x, const float* __restrict__ g0,
                             const float* __restrict__ g1, const float* __restrict__ g2,
                             __hip_bfloat16* __restrict__ h) {
    int idx = blockIdx.x * 256 + threadIdx.x;   // N*128
    int n = idx >> 7, c = idx & 127;
    float v;
    if (c < 32)       v = x[n * 32 + c];
    else if (c < 64)  v = g0[n * 32 + (c - 32)];
    else if (c < 96)  v = g1[n * 32 + (c - 64)];
    else              v = g2[n * 32 + (c - 96)];
    h[(size_t)n * 512 + 256 + c] = __float2bfloat16(v);
}

// ---------------- mean aggregation: branchless 8 edges/iter, unconditional prefetch ------
template <int DIM>
__global__ void gs_agg_bf(const __hip_bfloat16* __restrict__ hsrc,
                          __hip_bfloat16* __restrict__ adst,
                          const int* __restrict__ prow, const int* __restrict__ pcsr,
                          const float* __restrict__ inv_cnt) {
    int wave = threadIdx.x >> 6;
    int lane = threadIdx.x & 63;
    int n = blockIdx.x * 4 + wave;
    int e = prow[n], pe = prow[n + 1];
    float iv = inv_cnt[n];
    if constexpr (DIM == 256) {
        const __hip_bfloat16* base = hsrc + lane * 4;
        float a0 = 0.f, a1 = 0.f, a2 = 0.f, a3 = 0.f;
        int4 ia = *(const int4*)(pcsr + e);
        int4 ib = *(const int4*)(pcsr + e + 4);
        while (e < pe) {
            int4 c0 = ia, c1 = ib;
            e += 8;
            ia = *(const int4*)(pcsr + e);       // slack-backed over-read at tail
            ib = *(const int4*)(pcsr + e + 4);
            ushort4 v0 = *(const ushort4*)(base + (size_t)c0.x * 512);
            ushort4 v1 = *(const ushort4*)(base + (size_t)c0.y * 512);
            ushort4 v2 = *(const ushort4*)(base + (size_t)c0.z * 512);
            ushort4 v3 = *(const ushort4*)(base + (size_t)c0.w * 512);
            ushort4 v4 = *(const ushort4*)(base + (size_t)c1.x * 512);
            ushort4 v5 = *(const ushort4*)(base + (size_t)c1.y * 512);
            ushort4 v6 = *(const ushort4*)(base + (size_t)c1.z * 512);
            ushort4 v7 = *(const ushort4*)(base + (size_t)c1.w * 512);
            a0 += b2f(v0.x); a1 += b2f(v0.y); a2 += b2f(v0.z); a3 += b2f(v0.w);
            a0 += b2f(v1.x); a1 += b2f(v1.y); a2 += b2f(v1.z); a3 += b2f(v1.w);
            a0 += b2f(v2.x); a1 += b2f(v2.y); a2 += b2f(v2.z); a3 += b2f(v2.w);
            a0 += b2f(v3.x); a1 += b2f(v3.y); a2 += b2f(v3.z); a3 += b2f(v3.w);
            a0 += b2f(v4.x); a1 += b2f(v4.y); a2 += b2f(v4.z); a3 += b2f(v4.w);
            a0 += b2f(v5.x); a1 += b2f(v5.y); a2 += b2f(v5.z); a3 += b2f(v5.w);
            a0 += b2f(v6.x); a1 += b2f(v6.y); a2 += b2f(v6.z); a3 += b2f(v6.w);
            a0 += b2f(v7.x); a1 += b2f(v7.y); a2 += b2f(v7.z); a3 += b2f(v7.w);
        }
        __hip_bfloat16 o[4] = {__float2bfloat16(a0 * iv), __float2bfloat16(a1 * iv),
                               __float2bfloat16(a2 * iv), __float2bfloat16(a3 * iv)};
        *(ushort4*)(adst + (size_t)n * 512 + lane * 4) = *(const ushort4*)o;
    } else {
        const __hip_bfloat16* base = hsrc + lane * 2;
        float a0 = 0.f, a1 = 0.f;
        int4 ia = *(const int4*)(pcsr + e);
        int4 ib = *(const int4*)(pcsr + e + 4);
        while (e < pe) {
            int4 c0 = ia, c1 = ib;
            e += 8;
            ia = *(const int4*)(pcsr + e);
            ib = *(const int4*)(pcsr + e + 4);
            ushort2 v0 = *(const ushort2*)(base + (size_t)c0.x * 512);
            ushort2 v1 = *(const ushort2*)(base + (size_t)c0.y * 512);
            ushort2 v2 = *(const ushort2*)(base + (size_t)c0.z * 512);
            ushort2 v3 = *(const ushort2*)(base + (size_t)c0.w * 512);
            ushort2 v4 = *(const ushort2*)(base + (size_t)c1.x * 512);
            ushort2 v5 = *(const ushort2*)(base + (size_t)c1.y * 512);
            ushort2 v6 = *(const ushort2*)(base + (size_t)c1.z * 512);
            ushort2 v7 = *(const ushort2*)(base + (size_t)c1.w * 512);
            a0 += b2f(v0.x); a1 += b2f(v0.y);
            a0 += b2f(v1.x); a1 += b2f(v1.y);
            a0 += b2f(v2.x); a1 += b2f(v2.y);
            a0 += b2f(v3.x); a1 += b2f(v3.y);
            a0 += b2f(v4.x); a1 += b2f(v4.y);
            a0 += b2f(v5.x); a1 += b2f(v5.y);
            a0 += b2f(v6.x); a1 += b2f(v6.y);
            a0 += b2f(v7.x); a1 += b2f(v7.y);
        }
        __hip_bfloat16 o[2] = {__float2bfloat16(a0 * iv), __float2bfloat16(a1 * iv)};
        *(ushort2*)(adst + (size_t)n * 512 + lane * 2) = *(const ushort2*)o;
    }
}

// ---------------- MFMA GEMM core: 128x256 tile, BK=64, 4 waves (2x2 of 64x128) -----------
// Full N=256 per block -> A read ONCE. Operands swapped in the mfma call -> acc holds
// C^T fragments -> packed epilogue stores.
__device__ __forceinline__ void mfma_block_n256(const __hip_bfloat16* A, int lda,
                                                const __hip_bfloat16* Bt, int ldb,
                                                int kbeg, int kend, size_t row0,
                                                __hip_bfloat16* As, __hip_bfloat16* Bs,
                                                f32x4 acc[4][8]) {
    const int t = threadIdx.x;
    const int lane = t & 63;
    const int w = t >> 6;
    const int wr = (w >> 1) * 64;
    const int wc = (w & 1) * 128;
    const int sr8 = lane >> 3;          // 0..7
    const int scol = (lane & 7) * 8;    // 16B per lane
    for (int kc = kbeg; kc < kend; kc += 64) {
#pragma unroll
        for (int l = 0; l < 4; ++l)
            gld_lds16(A + (row0 + w * 32 + 8 * l + sr8) * (size_t)lda + kc + scol,
                      As + (w * 32 + 8 * l) * 64);
#pragma unroll
        for (int l = 0; l < 8; ++l)
            gld_lds16(Bt + (size_t)(w * 64 + 8 * l + sr8) * ldb + kc + scol,
                      Bs + (w * 64 + 8 * l) * 64);
        __syncthreads();
#pragma unroll
        for (int kk = 0; kk < 64; kk += 32) {
            frag16 af[4];
#pragma unroll
            for (int i = 0; i < 4; ++i)
                af[i] = *(const frag16*)(As + (wr + i * 16 + (lane & 15)) * 64 + kk + (lane >> 4) * 8);
#pragma unroll
            for (int j = 0; j < 8; ++j) {
                frag16 bf = *(const frag16*)(Bs + (wc + j * 16 + (lane & 15)) * 64 + kk + (lane >> 4) * 8);
#pragma unroll
                for (int i = 0; i < 4; ++i)
                    acc[i][j] = __builtin_amdgcn_mfma_f32_16x16x32_bf16(bf, af[i], acc[i][j], 0, 0, 0);
            }
        }
        __syncthreads();
    }
}

__global__ __launch_bounds__(256, 2)
void gs_gemm_bias_relu(const __hip_bfloat16* __restrict__ A, int lda, int K,
                       const __hip_bfloat16* __restrict__ Bt, int ldb,
                       const float* __restrict__ bias,
                       __hip_bfloat16* __restrict__ C, int ldc, int cofs) {
    __shared__ __hip_bfloat16 As[128 * 64];
    __shared__ __hip_bfloat16 Bs[256 * 64];
    f32x4 acc[4][8] = {};
    const size_t row0 = (size_t)blockIdx.x * 128;
    mfma_block_n256(A, lda, Bt, ldb, 0, K, row0, As, Bs, acc);
    const int lane = threadIdx.x & 63;
    const int w = threadIdx.x >> 6;
    const int wr = (w >> 1) * 64, wc = (w & 1) * 128;
#pragma unroll
    for (int j = 0; j < 8; ++j) {
        int nb = wc + j * 16 + (lane >> 4) * 4;
        const float4 bv = *(const float4*)&bias[nb];
#pragma unroll
        for (int i = 0; i < 4; ++i) {
            int m = wr + i * 16 + (lane & 15);
            unsigned short o[4];
            o[0] = f2b(fmaxf(acc[i][j][0] + bv.x, 0.f));
            o[1] = f2b(fmaxf(acc[i][j][1] + bv.y, 0.f));
            o[2] = f2b(fmaxf(acc[i][j][2] + bv.z, 0.f));
            o[3] = f2b(fmaxf(acc[i][j][3] + bv.w, 0.f));
            *(ushort4*)(C + (row0 + m) * (size_t)ldc + cofs + nb) = *(const ushort4*)o;
        }
    }
}

// MLP1 split-K: grid (16, 16); k-slice 512; fp32 partials part[kz][2048][256]
__global__ __launch_bounds__(256, 2)
void gs_gemm_splitk(const __hip_bfloat16* __restrict__ A, int lda,
                    const __hip_bfloat16* __restrict__ Bt, int ldb,
                    float* __restrict__ part) {
    __shared__ __hip_bfloat16 As[128 * 64];
    __shared__ __hip_bfloat16 Bs[256 * 64];
    f32x4 acc[4][8] = {};
    const size_t row0 = (size_t)blockIdx.x * 128;
    const int kbeg = blockIdx.y * 512;
    mfma_block_n256(A, lda, Bt, ldb, kbeg, kbeg + 512, row0, As, Bs, acc);
    const int lane = threadIdx.x & 63;
    const int w = threadIdx.x >> 6;
    const int wr = (w >> 1) * 64, wc = (w & 1) * 128;
    float* p = part + (size_t)blockIdx.y * 2048 * 256;
#pragma unroll
    for (int j = 0; j < 8; ++j) {
        int nb = wc + j * 16 + (lane >> 4) * 4;
#pragma unroll
        for (int i = 0; i < 4; ++i) {
            int m = wr + i * 16 + (lane & 15);
            *(f32x4*)(p + (row0 + m) * 256 + nb) = acc[i][j];
        }
    }
}

// fused: t1 = relu(sum_k part + b1); pooled[r] = t1 . W2 + b2   (block = one row)
__global__ void gs_mlp1_reduce_pool(const float* __restrict__ part,
                                    const float* __restrict__ b1,
                                    const float* __restrict__ W2,
                                    const float* __restrict__ b2,
                                    float* __restrict__ pooled) {
    __shared__ float w4[4];
    int r = blockIdx.x;            // 2048
    int t = threadIdx.x;           // 256
    size_t idx = (size_t)r * 256 + t;
    float s = 0.f;
#pragma unroll
    for (int ks = 0; ks < 16; ++ks) s += part[(size_t)ks * 524288 + idx];
    s = fmaxf(s + b1[t], 0.f) * W2[t];
#pragma unroll
    for (int off = 32; off > 0; off >>= 1) s += __shfl_down(s, off);
    if ((t & 63) == 0) w4[t >> 6] = s;
    __syncthreads();
    if (t == 0) pooled[r] = w4[0] + w4[1] + w4[2] + w4[3] + b2[0];
}

__global__ void gs_bn_mlp2(const float* __restrict__ pooled, const float* __restrict__ gamma,
                           const float* __restrict__ beta, const float* __restrict__ W1,
                           const float* __restrict__ b1, const float* __restrict__ W2,
                           const float* __restrict__ b2, float* __restrict__ out) {
    __shared__ float hb[8][256];
    __shared__ float h2[8][256];
    int t = threadIdx.x;    // 256
    {
        float v[8];
        float m = 0.f;
#pragma unroll
        for (int b = 0; b < 8; ++b) { v[b] = pooled[b * 256 + t]; m += v[b]; }
        m *= 0.125f;
        float var = 0.f;
#pragma unroll
        for (int b = 0; b < 8; ++b) { float d = v[b] - m; var += d * d; }
        var *= 0.125f;
        float is = 1.0f / sqrtf(var + 1e-5f);
        float g = gamma[t], bt = beta[t];
#pragma unroll
        for (int b = 0; b < 8; ++b) hb[b][t] = fmaxf((v[b] - m) * is * g + bt, 0.f);
    }
    __syncthreads();
    {
        float acc[8] = {};
        for (int i = 0; i < 256; ++i) {
            float w = W1[i * 256 + t];
#pragma unroll
            for (int b = 0; b < 8; ++b) acc[b] = fmaf(hb[b][i], w, acc[b]);
        }
        float bb = b1[t];
#pragma unroll
        for (int b = 0; b < 8; ++b) h2[b][t] = fmaxf(acc[b] + bb, 0.f);
    }
    __syncthreads();
    if (t < 64) {
        int b = t >> 3, o = t & 7;
        float acc = 0.f;
        for (int j = 0; j < 256; ++j) acc = fmaf(h2[b][j], W2[j * 8 + o], acc);
        out[b * 8 + o] = acc + b2[o];
    }
}

extern "C" void kernel_launch(void* const* d_in, const int* in_sizes, int n_in,
                              void* d_out, int out_size, void* d_ws, size_t ws_size,
                              hipStream_t stream) {
    const float* x  = (const float*)d_in[0];
    const float* g0 = (const float*)d_in[1];
    const float* g1 = (const float*)d_in[2];
    const float* g2 = (const float*)d_in[3];
    const int* edge_src = (const int*)d_in[4];
    const int* edge_dst = (const int*)d_in[5];
    const float* Wl[4] = {(const float*)d_in[6], (const float*)d_in[9],
                          (const float*)d_in[12], (const float*)d_in[15]};
    const float* Wr[4] = {(const float*)d_in[7], (const float*)d_in[10],
                          (const float*)d_in[13], (const float*)d_in[16]};
    const float* bs[4] = {(const float*)d_in[8], (const float*)d_in[11],
                          (const float*)d_in[14], (const float*)d_in[17]};
    const float* mlp1_W1 = (const float*)d_in[18];
    const float* mlp1_b1 = (const float*)d_in[19];
    const float* mlp1_W2 = (const float*)d_in[20];
    const float* mlp1_b2 = (const float*)d_in[21];
    const float* bn_gamma = (const float*)d_in[22];
    const float* bn_beta  = (const float*)d_in[23];
    const float* mlp2_W1 = (const float*)d_in[24];
    const float* mlp2_b1 = (const float*)d_in[25];
    const float* mlp2_W2 = (const float*)d_in[26];
    const float* mlp2_b2 = (const float*)d_in[27];
    float* out = (float*)d_out;

    char* ws = (char*)d_ws;
    __hip_bfloat16* P0 = (__hip_bfloat16*)ws;                  // [ROWS][512]
    __hip_bfloat16* P1 = P0 + (size_t)ROWS * 512;              // [ROWS][512]
    __hip_bfloat16* WC0 = P1 + (size_t)ROWS * 512;             // [256][256]
    __hip_bfloat16* WC1 = WC0 + 65536;                         // [256][512]
    __hip_bfloat16* WC2 = WC1 + 131072;
    __hip_bfloat16* WC3 = WC2 + 131072;
    __hip_bfloat16* W1T = WC3 + 131072;                        // [256][8192]
    float* inv_cnt = (float*)(W1T + 2097152);
    int* ideg = (int*)(inv_cnt + 65536);
    int* prow = ideg + 65536;                                  // 65537 (+pad)
    int* cursor = prow + 65544;
    int* bsum = cursor + 65536;                                // 256
    int* bofs = bsum + 256;                                    // 256
    int* pcsr = bofs + 256;                                    // PCSR_CAP (incl. slack)
    // overlays (all inside P0/P1, mutually disjoint):
    __hip_bfloat16* H4 = P0;                                   // [2048][8192] bf16 = 32 MB
    float* pooled = (float*)((char*)P1 + (size_t)(2 << 20));   // 8 KB at P1+2MB
    float* PART = (float*)((char*)P1 + (size_t)(4 << 20));     // 32 MB at P1+4MB

    // --- graph prep (hierarchical scan; apply pad-fills pcsr + zeroes pad rows) ---
    gs_zero_deg<<<256, 256, 0, stream>>>(ideg);
    gs_hist<<<EE / 256, 256, 0, stream>>>(edge_dst, ideg);
    gs_deg_reduce<<<256, 256, 0, stream>>>(ideg, bsum);
    gs_scan_bsum<<<1, 256, 0, stream>>>(bsum, bofs, prow);
    gs_scan_apply<<<256, 256, 0, stream>>>(ideg, bofs, prow, cursor, inv_cnt, pcsr, P0, P1);
    gs_bucket<<<EE / 256, 256, 0, stream>>>(edge_src, edge_dst, cursor, pcsr);

    // --- weight conversion (one fused launch + W1T) ---
    {
        TcvtArgs a;
        const float* srcs[8] = {Wl[0], Wr[0], Wl[1], Wr[1], Wl[2], Wr[2], Wl[3], Wr[3]};
        __hip_bfloat16* dsts[8] = {WC0, WC0, WC1, WC1, WC2, WC2, WC3, WC3};
        int ldks[8] = {256, 256, 512, 512, 512, 512, 512, 512};
        int kofss[8] = {0, 128, 0, 256, 0, 256, 0, 256};
        int kblks[8] = {4, 4, 8, 8, 8, 8, 8, 8};
        for (int i = 0; i < 8; ++i) {
            a.src[i] = srcs[i]; a.dst[i] = dsts[i];
            a.ldk[i] = ldks[i]; a.kofs[i] = kofss[i]; a.kblk[i] = kblks[i];
        }
        gs_tcvt_all<<<dim3(8, 8, 8), dim3(32, 8), 0, stream>>>(a);
    }
    gs_tcvt<<<dim3(256, 8), dim3(32, 8), 0, stream>>>(mlp1_W1, W1T, 8192, 0);

    gs_concat_bf<<<NN * 128 / 256, 256, 0, stream>>>(x, g0, g1, g2, P0);

    // --- 4 SAGE layers (N-tile 256: grid = M/128 blocks, A read once) ---
    gs_agg_bf<128><<<NN / 4, 256, 0, stream>>>(P0 + 256, P0 + 128, prow, pcsr, inv_cnt);
    gs_gemm_bias_relu<<<NN / 128, 256, 0, stream>>>(P0 + 128, 512, 256, WC0, 256,
                                                    bs[0], P1, 512, 256);
    gs_agg_bf<256><<<NN / 4, 256, 0, stream>>>(P1 + 256, P1, prow, pcsr, inv_cnt);
    gs_gemm_bias_relu<<<NN / 128, 256, 0, stream>>>(P1, 512, 512, WC1, 512,
                                                    bs[1], P0, 512, 256);
    gs_agg_bf<256><<<NN / 4, 256, 0, stream>>>(P0 + 256, P0, prow, pcsr, inv_cnt);
    gs_gemm_bias_relu<<<NN / 128, 256, 0, stream>>>(P0, 512, 512, WC2, 512,
                                                    bs[2], P1, 512, 256);
    gs_agg_bf<256><<<NN / 4, 256, 0, stream>>>(P1 + 256, P1, prow, pcsr, inv_cnt);
    gs_gemm_bias_relu<<<NN / 128, 256, 0, stream>>>(P1, 512, 512, WC3, 512,
                                                    bs[3], H4, 256, 0);

    // --- MLP1: [2048,8192] @ [8192,256] bf16 split-K=16 -> fp32 partials -> pooled ---
    gs_gemm_splitk<<<dim3(16, 16), 256, 0, stream>>>(H4, 8192, W1T, 8192, PART);
    gs_mlp1_reduce_pool<<<2048, 256, 0, stream>>>(PART, mlp1_b1, mlp1_W2, mlp1_b2, pooled);

    // --- BN + MLP2 -> out[8,8] ---
    gs_bn_mlp2<<<1, 256, 0, stream>>>(pooled, bn_gamma, bn_beta, mlp2_W1, mlp2_b1,
                                      mlp2_W2, mlp2_b2, out);
}